// Round 2
// baseline (566.199 us; speedup 1.0000x reference)
//
#include <hip/hip_runtime.h>
#include <hip/hip_bf16.h>
#include <math.h>

#define DD 256
#define HH 128
#define OO 64

#define EPB 8192          // edges per partition block
#define BKT 512           // nodes per bucket (bucket = idx >> 9)

typedef __attribute__((ext_vector_type(8))) __bf16 bf16x8;
typedef __attribute__((ext_vector_type(4))) __bf16 bf16x4;
typedef __attribute__((ext_vector_type(4))) float f32x4;

__device__ inline float2 bf2_to_f2(unsigned u) {
    float2 r;
    r.x = __uint_as_float(u << 16);
    r.y = __uint_as_float(u & 0xffff0000u);
    return r;
}

// ---------------------------------------------------------------------------
// K1: per-block LDS histograms over coarse buckets (both col and row sides)
// ---------------------------------------------------------------------------
__global__ void part_count_kernel(const int* __restrict__ row, const int* __restrict__ col,
                                  int e, int nb,
                                  int* __restrict__ cnt_col, int* __restrict__ cnt_row) {
    __shared__ int hc[256], hr[256];
    int t = threadIdx.x;
    hc[t] = 0; hr[t] = 0;
    __syncthreads();
    int base = blockIdx.x * EPB;
    int lim  = min(EPB, e - base);
    for (int i = t; i < lim; i += 256) {
        atomicAdd(&hc[col[base + i] >> 9], 1);
        atomicAdd(&hr[row[base + i] >> 9], 1);
    }
    __syncthreads();
    if (t < nb) {
        cnt_col[blockIdx.x * nb + t] = hc[t];
        cnt_row[blockIdx.x * nb + t] = hr[t];
    }
}

// ---------------------------------------------------------------------------
// K2a: one block per (side,bucket): scan nblk per-block counts -> bases+total
// ---------------------------------------------------------------------------
__global__ void scan_blocks_kernel(const int* __restrict__ cnt_col, const int* __restrict__ cnt_row,
                                   int* __restrict__ base_col, int* __restrict__ base_row,
                                   int* __restrict__ tot_col, int* __restrict__ tot_row,
                                   int nblk, int nb) {
    __shared__ int s[256];
    int side = (blockIdx.x >= (unsigned)nb) ? 1 : 0;
    int b = blockIdx.x - side * nb;
    const int* cnt = side ? cnt_row : cnt_col;
    int* base = side ? base_row : base_col;
    int* tot  = side ? tot_row  : tot_col;
    int t = threadIdx.x;
    int v = (t < nblk) ? cnt[(size_t)t * nb + b] : 0;
    s[t] = v;
    __syncthreads();
    for (int off = 1; off < 256; off <<= 1) {
        int u = (t >= off) ? s[t - off] : 0;
        __syncthreads();
        s[t] += u;
        __syncthreads();
    }
    if (t < nblk) base[(size_t)t * nb + b] = s[t] - v;
    if (t == 255) tot[b] = s[255];
}

// ---------------------------------------------------------------------------
// K2b: one block: exclusive scan of both totals arrays -> bucket bases
// ---------------------------------------------------------------------------
__global__ void scan_tots_kernel(const int* __restrict__ tot_col, const int* __restrict__ tot_row,
                                 int* __restrict__ bb_col, int* __restrict__ bb_row, int nb) {
    __shared__ int s[256];
    int t = threadIdx.x;
    int v = (t < nb) ? tot_col[t] : 0;
    s[t] = v;
    __syncthreads();
    for (int off = 1; off < 256; off <<= 1) {
        int u = (t >= off) ? s[t - off] : 0;
        __syncthreads();
        s[t] += u;
        __syncthreads();
    }
    if (t < nb) bb_col[t] = s[t] - v;
    __syncthreads();
    int v2 = (t < nb) ? tot_row[t] : 0;
    s[t] = v2;
    __syncthreads();
    for (int off = 1; off < 256; off <<= 1) {
        int u = (t >= off) ? s[t - off] : 0;
        __syncthreads();
        s[t] += u;
        __syncthreads();
    }
    if (t < nb) bb_row[t] = s[t] - v2;
}

// ---------------------------------------------------------------------------
// K2c: add bucket bases into per-block bases; also row_ptr[n] = e
// ---------------------------------------------------------------------------
__global__ void add_bases_kernel(int* __restrict__ base_col, int* __restrict__ base_row,
                                 const int* __restrict__ bb_col, const int* __restrict__ bb_row,
                                 int* __restrict__ row_ptr, int n, int e, int nblk, int nb) {
    int side = (blockIdx.x >= (unsigned)nb) ? 1 : 0;
    int b = blockIdx.x - side * nb;
    int* base = side ? base_row : base_col;
    int add   = side ? bb_row[b] : bb_col[b];
    for (int t = threadIdx.x; t < nblk; t += blockDim.x) base[(size_t)t * nb + b] += add;
    if (blockIdx.x == 0 && threadIdx.x == 0) row_ptr[n] = e;
}

// ---------------------------------------------------------------------------
// K3: scatter edges into bucket-major temps via LDS cursors
// ---------------------------------------------------------------------------
__global__ void part_scatter_kernel(const int* __restrict__ row, const int* __restrict__ col,
                                    const float* __restrict__ ppmi,
                                    const int* __restrict__ base_col, const int* __restrict__ base_row,
                                    int4* __restrict__ tmp_col, int2* __restrict__ tmp_row,
                                    int e, int nb) {
    __shared__ int cc[256], cr[256];
    int t = threadIdx.x;
    if (t < nb) {
        cc[t] = base_col[blockIdx.x * nb + t];
        cr[t] = base_row[blockIdx.x * nb + t];
    }
    __syncthreads();
    int base = blockIdx.x * EPB;
    int lim  = min(EPB, e - base);
    for (int i = t; i < lim; i += 256) {
        int r = row[base + i], c = col[base + i];
        int w = __float_as_int(ppmi[base + i]);
        int sc = atomicAdd(&cc[c >> 9], 1);
        tmp_col[sc] = make_int4(c, r, w, 0);
        int sr = atomicAdd(&cr[r >> 9], 1);
        tmp_row[sr] = make_int2(r, w);
    }
}

// ---------------------------------------------------------------------------
// K4b: per-row-bucket degree accumulation in LDS -> dis (float2: {g, p})
// ---------------------------------------------------------------------------
__global__ void deg_bucket_kernel(const int2* __restrict__ tmp_row,
                                  const int* __restrict__ bb_row, const int* __restrict__ tot_row,
                                  float2* __restrict__ dis, int n) {
    __shared__ float dg[BKT], dp[BKT];
    int t = threadIdx.x;
    for (int j = t; j < BKT; j += 256) { dg[j] = 1.0f; dp[j] = 1.0f; }  // self-loop
    __syncthreads();
    int b = blockIdx.x;
    int beg = bb_row[b], cnt = tot_row[b];
    for (int i = t; i < cnt; i += 256) {
        int2 cell = tmp_row[beg + i];
        int lr = cell.x & (BKT - 1);
        atomicAdd(&dg[lr], 1.0f);
        atomicAdd(&dp[lr], __int_as_float(cell.y));
    }
    __syncthreads();
    int rb = b << 9;
    for (int j = t; j < BKT; j += 256) {
        int g = rb + j;
        if (g < n) dis[g] = make_float2(rsqrtf(dg[j]), rsqrtf(dp[j]));
    }
}

// ---------------------------------------------------------------------------
// K4: per-col-bucket CSR finalize -> packed edge meta {src, wg, wp, 0}
// ---------------------------------------------------------------------------
__launch_bounds__(512)
__global__ void csr_bucket_kernel(const int4* __restrict__ tmp_col,
                                  const int* __restrict__ bb_col, const int* __restrict__ tot_col,
                                  const float2* __restrict__ dis,
                                  int* __restrict__ row_ptr, int4* __restrict__ csr_meta, int n) {
    __shared__ int hist[BKT], s[BKT], cur[BKT];
    int t = threadIdx.x;   // 512 threads
    hist[t] = 0;
    __syncthreads();
    int b = blockIdx.x;
    int beg = bb_col[b], cnt = tot_col[b];
    for (int i = t; i < cnt; i += BKT) atomicAdd(&hist[tmp_col[beg + i].x & (BKT - 1)], 1);
    __syncthreads();
    int own = hist[t];
    s[t] = own;
    __syncthreads();
    for (int off = 1; off < BKT; off <<= 1) {
        int v = (t >= off) ? s[t - off] : 0;
        __syncthreads();
        s[t] += v;
        __syncthreads();
    }
    int gslot = beg + s[t] - own;
    cur[t] = gslot;
    int gc = (b << 9) + t;
    if (gc < n) row_ptr[gc] = gslot;
    __syncthreads();
    for (int i = t; i < cnt; i += BKT) {
        int4 cell = tmp_col[beg + i];
        int lc = cell.x & (BKT - 1);
        int slot = atomicAdd(&cur[lc], 1);
        int r = cell.y;
        float w = __int_as_float(cell.z);
        float2 d = dis[r];
        csr_meta[slot] = make_int4(r, __float_as_int(d.x), __float_as_int(d.y * w), 0);
    }
}

// ---------------------------------------------------------------------------
// W -> B^T split-bf16 prep
// ---------------------------------------------------------------------------
__global__ void conv_w_kernel(const float* __restrict__ W, __bf16* __restrict__ Bh,
                              __bf16* __restrict__ Bl, int K, int N) {
    int i = blockIdx.x * blockDim.x + threadIdx.x;
    if (i >= K * N) return;
    int k = i / N, nn = i % N;
    float v = W[i];
    __bf16 h = (__bf16)v;
    Bh[(size_t)nn * K + k] = h;
    Bl[(size_t)nn * K + k] = (__bf16)(v - (float)h);
}

// ---------------------------------------------------------------------------
// Split-bf16 MFMA GEMM: C[M,BN] = A[M,K] @ B[K,BN]; OT = fp32 or bf16 output.
// ILV: interleave rows [0,nHalf) and [nHalf,2*nHalf) as C[c][col][{0,1}].
// ---------------------------------------------------------------------------
template<int BM, int BN, typename OT, bool ILV>
__launch_bounds__(256, 2)
__global__ void mfma_gemm_kernel(const float* __restrict__ A,
                                 const __bf16* __restrict__ Bth, const __bf16* __restrict__ Btl,
                                 OT* __restrict__ C, int M, int K, int nHalf) {
    constexpr int BK  = 32;
    constexpr int LDK = BK + 8;
    constexpr int WM  = BM / 4;
    constexpr int MT  = WM / 16;
    constexpr int NT  = BN / 16;
    __shared__ __bf16 Ash[BM * LDK];
    __shared__ __bf16 Asl[BM * LDK];
    __shared__ __bf16 Bsh[BN * LDK];
    __shared__ __bf16 Bsl[BN * LDK];

    const int tid  = threadIdx.x;
    const int wave = tid >> 6;
    const int lane = tid & 63;
    const int quad = lane >> 4;
    const int l16  = lane & 15;
    const int row0 = blockIdx.x * BM;

    f32x4 acc[MT][NT] = {};

    for (int k0 = 0; k0 < K; k0 += BK) {
#pragma unroll
        for (int p = 0; p < BM / 32; ++p) {
            int lin = p * 256 + tid;
            int r   = lin >> 3;
            int kc  = (lin & 7) * 4;
            int gr  = row0 + r;
            float4 v;
            if (gr < M) v = *(const float4*)(A + (size_t)gr * K + k0 + kc);
            else        v = make_float4(0.f, 0.f, 0.f, 0.f);
            __bf16 h0 = (__bf16)v.x, h1 = (__bf16)v.y, h2 = (__bf16)v.z, h3 = (__bf16)v.w;
            __bf16 l0 = (__bf16)(v.x - (float)h0), l1 = (__bf16)(v.y - (float)h1);
            __bf16 l2 = (__bf16)(v.z - (float)h2), l3 = (__bf16)(v.w - (float)h3);
            *(bf16x4*)&Ash[r * LDK + kc] = (bf16x4){h0, h1, h2, h3};
            *(bf16x4*)&Asl[r * LDK + kc] = (bf16x4){l0, l1, l2, l3};
        }
#pragma unroll
        for (int p = 0; p < BN / 64; ++p) {
            int lin = p * 256 + tid;
            int r   = lin >> 2;
            int kc  = (lin & 3) * 8;
            *(uint4*)&Bsh[r * LDK + kc] = *(const uint4*)(Bth + (size_t)r * K + k0 + kc);
            *(uint4*)&Bsl[r * LDK + kc] = *(const uint4*)(Btl + (size_t)r * K + k0 + kc);
        }
        __syncthreads();

        bf16x8 bh[NT], bl[NT];
#pragma unroll
        for (int j = 0; j < NT; ++j) {
            bh[j] = *(const bf16x8*)&Bsh[(j * 16 + l16) * LDK + quad * 8];
            bl[j] = *(const bf16x8*)&Bsl[(j * 16 + l16) * LDK + quad * 8];
        }
#pragma unroll
        for (int i = 0; i < MT; ++i) {
            int m = wave * WM + i * 16 + l16;
            bf16x8 ah = *(const bf16x8*)&Ash[m * LDK + quad * 8];
            bf16x8 al = *(const bf16x8*)&Asl[m * LDK + quad * 8];
#pragma unroll
            for (int j = 0; j < NT; ++j) {
                acc[i][j] = __builtin_amdgcn_mfma_f32_16x16x32_bf16(ah, bh[j], acc[i][j], 0, 0, 0);
                acc[i][j] = __builtin_amdgcn_mfma_f32_16x16x32_bf16(ah, bl[j], acc[i][j], 0, 0, 0);
                acc[i][j] = __builtin_amdgcn_mfma_f32_16x16x32_bf16(al, bh[j], acc[i][j], 0, 0, 0);
            }
        }
        __syncthreads();
    }

#pragma unroll
    for (int i = 0; i < MT; ++i) {
#pragma unroll
        for (int rg = 0; rg < 4; ++rg) {
            int gr = row0 + wave * WM + i * 16 + quad * 4 + rg;
            if (gr < M) {
                if constexpr (ILV) {
                    int s = (gr >= nHalf) ? 1 : 0;
                    size_t base = (size_t)(gr - s * nHalf) * (BN * 2) + s;
#pragma unroll
                    for (int j = 0; j < NT; ++j)
                        C[base + (size_t)(j * 16 + l16) * 2] = (OT)acc[i][j][rg];
                } else {
#pragma unroll
                    for (int j = 0; j < NT; ++j)
                        C[(size_t)gr * BN + j * 16 + l16] = (OT)acc[i][j][rg];
                }
            }
        }
    }
}

// ---------------------------------------------------------------------------
// Layer-1 pull aggregation: one wave per node, edge-PAIR per iteration:
// lanes 0-31 handle edge t, lanes 32-63 edge t+1; each lane gathers 8 B
// (4 features). 4 pair-slots (8 edges) per loop iter, clamp-predicated
// (clamped slots re-hit the last row -> cache-hit cheap).
// ---------------------------------------------------------------------------
__global__ void agg1_pull_kernel(const int* __restrict__ row_ptr, const int4* __restrict__ meta,
                                 const __bf16* __restrict__ hw1,
                                 const float2* __restrict__ dis,
                                 const float* __restrict__ b1,
                                 float* __restrict__ g_out, float* __restrict__ p_out, int n) {
    int c    = blockIdx.x * 4 + (threadIdx.x >> 6);
    int lane = threadIdx.x & 63;
    if (c >= n) return;
    int eh = lane >> 5;            // which edge of the pair this lane owns
    int f4 = (lane & 31) * 4;      // 4 features per lane
    int beg = row_ptr[c], end = row_ptr[c + 1];
    float sg0 = 0.f, sg1 = 0.f, sg2 = 0.f, sg3 = 0.f;
    float sp0 = 0.f, sp1 = 0.f, sp2 = 0.f, sp3 = 0.f;
    for (int t = beg; t < end; t += 8) {
#pragma unroll
        for (int q = 0; q < 4; ++q) {
            int i  = t + q * 2 + eh;
            int ic = min(i, end - 1);
            int4 m = meta[ic];
            float wg = (i < end) ? __int_as_float(m.y) : 0.f;
            float wp = (i < end) ? __int_as_float(m.z) : 0.f;
            uint2 u = *(const uint2*)(hw1 + ((size_t)m.x << 7) + f4);
            float2 hA = bf2_to_f2(u.x), hB = bf2_to_f2(u.y);
            sg0 += wg * hA.x; sg1 += wg * hA.y; sg2 += wg * hB.x; sg3 += wg * hB.y;
            sp0 += wp * hA.x; sp1 += wp * hA.y; sp2 += wp * hB.x; sp3 += wp * hB.y;
        }
    }
    // combine the two edge-halves; afterwards both halves hold full sums
    sg0 += __shfl_xor(sg0, 32, 64); sg1 += __shfl_xor(sg1, 32, 64);
    sg2 += __shfl_xor(sg2, 32, 64); sg3 += __shfl_xor(sg3, 32, 64);
    sp0 += __shfl_xor(sp0, 32, 64); sp1 += __shfl_xor(sp1, 32, 64);
    sp2 += __shfl_xor(sp2, 32, 64); sp3 += __shfl_xor(sp3, 32, 64);

    float2 d = dis[c];
    size_t rbase = ((size_t)c << 7) + f4;
    uint2 us = *(const uint2*)(hw1 + rbase);
    float2 hA = bf2_to_f2(us.x), hB = bf2_to_f2(us.y);
    float4 bv = *(const float4*)(b1 + f4);
    // lanes 0-31 produce/store the g row, lanes 32-63 the p row
    float dd = eh ? d.y : d.x;
    float v0 = eh ? sp0 : sg0, v1 = eh ? sp1 : sg1;
    float v2 = eh ? sp2 : sg2, v3 = eh ? sp3 : sg3;
    float r0 = dd * v0 + dd * dd * hA.x + bv.x;
    float r1 = dd * v1 + dd * dd * hA.y + bv.y;
    float r2 = dd * v2 + dd * dd * hB.x + bv.z;
    float r3 = dd * v3 + dd * dd * hB.y + bv.w;
    r0 = r0 > 0.f ? r0 : 0.f;  r1 = r1 > 0.f ? r1 : 0.f;
    r2 = r2 > 0.f ? r2 : 0.f;  r3 = r3 > 0.f ? r3 : 0.f;
    float* op = eh ? p_out : g_out;
    *(float4*)(op + rbase) = make_float4(r0, r1, r2, r3);
}

// ---------------------------------------------------------------------------
// Layer-2 pull aggregation + self-loop + bias + softmax gate.
// hw2i layout: [n][64][2] bf16 -> each lane gathers 8 B = 2 features x {g,p}.
// Edge-pair per iteration as in agg1.
// ---------------------------------------------------------------------------
__global__ void agg2_final_kernel(const int* __restrict__ row_ptr, const int4* __restrict__ meta,
                                  const __bf16* __restrict__ hw2i,
                                  const float2* __restrict__ dis,
                                  const float* __restrict__ b2,
                                  const float* __restrict__ dense_w, const float* __restrict__ dense_b,
                                  float* __restrict__ out, int n) {
    int c    = blockIdx.x * 4 + (threadIdx.x >> 6);
    int lane = threadIdx.x & 63;
    if (c >= n) return;
    int eh = lane >> 5;
    int fb = (lane & 31) * 2;      // 2 features per lane
    int beg = row_ptr[c], end = row_ptr[c + 1];
    float sg0 = 0.f, sg1 = 0.f, sp0 = 0.f, sp1 = 0.f;
    for (int t = beg; t < end; t += 8) {
#pragma unroll
        for (int q = 0; q < 4; ++q) {
            int i  = t + q * 2 + eh;
            int ic = min(i, end - 1);
            int4 m = meta[ic];
            float wg = (i < end) ? __int_as_float(m.y) : 0.f;
            float wp = (i < end) ? __int_as_float(m.z) : 0.f;
            uint2 u = *(const uint2*)(hw2i + ((size_t)m.x << 7) + fb * 2);
            float2 a = bf2_to_f2(u.x);   // a.x = g(fb),   a.y = p(fb)
            float2 b = bf2_to_f2(u.y);   // b.x = g(fb+1), b.y = p(fb+1)
            sg0 += wg * a.x; sp0 += wp * a.y;
            sg1 += wg * b.x; sp1 += wp * b.y;
        }
    }
    sg0 += __shfl_xor(sg0, 32, 64); sg1 += __shfl_xor(sg1, 32, 64);
    sp0 += __shfl_xor(sp0, 32, 64); sp1 += __shfl_xor(sp1, 32, 64);

    float2 d = dis[c];
    uint2 us = *(const uint2*)(hw2i + ((size_t)c << 7) + fb * 2);
    float2 a = bf2_to_f2(us.x), b = bf2_to_f2(us.y);
    float2 bv = *(const float2*)(b2 + fb);
    float gv0 = d.x * sg0 + d.x * d.x * a.x + bv.x;
    float pv0 = d.y * sp0 + d.y * d.y * a.y + bv.x;
    float gv1 = d.x * sg1 + d.x * d.x * b.x + bv.y;
    float pv1 = d.y * sp1 + d.y * d.y * b.y + bv.y;
    float2 dwv = *(const float2*)(dense_w + fb);
    float lg = gv0 * dwv.x + gv1 * dwv.y;
    float lp = pv0 * dwv.x + pv1 * dwv.y;
    // both 32-lane halves hold identical per-feature values; reduce within half
#pragma unroll
    for (int off = 16; off > 0; off >>= 1) {
        lg += __shfl_xor(lg, off, 64);
        lp += __shfl_xor(lp, off, 64);
    }
    lg += dense_b[0];
    lp += dense_b[0];
    float mm = fmaxf(lg, lp);
    float eg = expf(lg - mm), ep = expf(lp - mm);
    float wgt = eg / (eg + ep);
    float o0 = wgt * gv0 + (1.0f - wgt) * pv0;
    float o1 = wgt * gv1 + (1.0f - wgt) * pv1;
    if (eh == 0)
        *(float2*)(out + (size_t)c * OO + fb) = make_float2(o0, o1);
}

// ---------------------------------------------------------------------------
extern "C" void kernel_launch(void* const* d_in, const int* in_sizes, int n_in,
                              void* d_out, int out_size, void* d_ws, size_t ws_size,
                              hipStream_t stream) {
    const float* x    = (const float*)d_in[0];
    const int*   ei   = (const int*)d_in[1];
    const float* ppmi = (const float*)d_in[2];
    const float* W1   = (const float*)d_in[3];
    const float* b1   = (const float*)d_in[4];
    const float* W2   = (const float*)d_in[5];
    const float* b2   = (const float*)d_in[6];
    const float* dw   = (const float*)d_in[7];
    const float* db   = (const float*)d_in[8];
    float* out = (float*)d_out;

    const int n = in_sizes[0] / DD;       // 100000
    const int e = in_sizes[2];            // 1600000
    const int* row = ei;
    const int* col = ei + e;

    const int nb   = (n + BKT - 1) / BKT;   // buckets (<=256 required)
    const int nblk = (e + EPB - 1) / EPB;   // partition blocks (<=256 required)

    // ---- workspace layout ----
    float* ws      = (float*)d_ws;
    float2* dis    = (float2*)ws;                     // n float2
    __bf16* hw1    = (__bf16*)(ws + 2 * (size_t)n);   // n*128 bf16 (aliased as hw2i [n][64][2])
    float* g1      = (float*)(hw1 + (size_t)n * HH);  // n*128 f32 (tmp_col aliases: int4[e])
    float* p1      = g1 + (size_t)n * HH;             // n*128 f32 (tmp_row aliases: int2[e])
    int4* csr_meta = (int4*)(p1 + (size_t)n * HH);    // e int4 {src, wg, wp, 0}
    __bf16* bt1h   = (__bf16*)(csr_meta + e);         // DD*HH
    __bf16* bt1l   = bt1h + (size_t)DD * HH;
    __bf16* bt2h   = bt1l + (size_t)DD * HH;          // HH*OO
    __bf16* bt2l   = bt2h + (size_t)HH * OO;
    int* row_ptr   = (int*)(bt2l + (size_t)HH * OO);  // n+1
    int* cnt_col   = row_ptr + (n + 1);               // nblk*nb
    int* base_col  = cnt_col + (size_t)nblk * nb;     // nblk*nb
    int* cnt_row   = base_col + (size_t)nblk * nb;    // nblk*nb
    int* base_row  = cnt_row + (size_t)nblk * nb;     // nblk*nb
    int* bb_col    = base_row + (size_t)nblk * nb;    // nb
    int* tot_col   = bb_col + nb;                     // nb
    int* bb_row    = tot_col + nb;                    // nb
    int* tot_row   = bb_row + nb;                     // nb
    int4* tmp_col  = (int4*)g1;                       // e (alias, dead before agg1 writes g1)
    int2* tmp_row  = (int2*)p1;                       // e (alias, dead before agg1 writes p1)
    __bf16* hw2i   = hw1;                             // [n][64][2] bf16 (hw1 dead after agg1)

    const int T = 256;

    // ---- partition pipeline (LDS atomics only, fully parallel scans) ----
    part_count_kernel<<<nblk, T, 0, stream>>>(row, col, e, nb, cnt_col, cnt_row);
    scan_blocks_kernel<<<2 * nb, T, 0, stream>>>(cnt_col, cnt_row, base_col, base_row,
                                                 tot_col, tot_row, nblk, nb);
    scan_tots_kernel<<<1, T, 0, stream>>>(tot_col, tot_row, bb_col, bb_row, nb);
    add_bases_kernel<<<2 * nb, T, 0, stream>>>(base_col, base_row, bb_col, bb_row,
                                               row_ptr, n, e, nblk, nb);
    part_scatter_kernel<<<nblk, T, 0, stream>>>(row, col, ppmi, base_col, base_row,
                                                tmp_col, tmp_row, e, nb);
    deg_bucket_kernel<<<nb, T, 0, stream>>>(tmp_row, bb_row, tot_row, dis, n);
    csr_bucket_kernel<<<nb, BKT, 0, stream>>>(tmp_col, bb_col, tot_col, dis,
                                              row_ptr, csr_meta, n);

    // ---- weight prep ----
    conv_w_kernel<<<(DD * HH + T - 1) / T, T, 0, stream>>>(W1, bt1h, bt1l, DD, HH);
    conv_w_kernel<<<(HH * OO + T - 1) / T, T, 0, stream>>>(W2, bt2h, bt2l, HH, OO);

    // ---- network ----
    mfma_gemm_kernel<128, HH, __bf16, false><<<(n + 127) / 128, 256, 0, stream>>>(
        x, bt1h, bt1l, hw1, n, DD, 0);
    agg1_pull_kernel<<<(n + 3) / 4, 256, 0, stream>>>(row_ptr, csr_meta, hw1, dis, b1, g1, p1, n);
    mfma_gemm_kernel<128, OO, __bf16, true><<<(2 * n + 127) / 128, 256, 0, stream>>>(
        g1, bt2h, bt2l, hw2i, 2 * n, HH, n);
    agg2_final_kernel<<<(n + 3) / 4, 256, 0, stream>>>(row_ptr, csr_meta, hw2i, dis,
                                                       b2, dw, db, out, n);
}

// Round 3
// 524.830 us; speedup vs baseline: 1.0788x; 1.0788x over previous
//
#include <hip/hip_runtime.h>
#include <hip/hip_bf16.h>
#include <math.h>

#define DD 256
#define HH 128
#define OO 64

#define EPB 8192          // edges per partition block
#define BKT 512           // nodes per bucket (bucket = idx >> 9)

typedef __attribute__((ext_vector_type(8))) __bf16 bf16x8;
typedef __attribute__((ext_vector_type(4))) __bf16 bf16x4;
typedef __attribute__((ext_vector_type(4))) float f32x4;

__device__ inline float2 bf2_to_f2(unsigned u) {
    float2 r;
    r.x = __uint_as_float(u << 16);
    r.y = __uint_as_float(u & 0xffff0000u);
    return r;
}

// ---------------------------------------------------------------------------
// K1: per-block LDS histograms over coarse buckets (both col and row sides)
// 512 threads: partition blocks are few (196) -> need waves in flight.
// ---------------------------------------------------------------------------
__global__ void part_count_kernel(const int* __restrict__ row, const int* __restrict__ col,
                                  int e, int nb,
                                  int* __restrict__ cnt_col, int* __restrict__ cnt_row) {
    __shared__ int hc[256], hr[256];
    int t = threadIdx.x;
    if (t < 256) { hc[t] = 0; hr[t] = 0; }
    __syncthreads();
    int base = blockIdx.x * EPB;
    int lim  = min(EPB, e - base);
    for (int i = t; i < lim; i += 512) {
        atomicAdd(&hc[col[base + i] >> 9], 1);
        atomicAdd(&hr[row[base + i] >> 9], 1);
    }
    __syncthreads();
    if (t < nb) {
        cnt_col[blockIdx.x * nb + t] = hc[t];
        cnt_row[blockIdx.x * nb + t] = hr[t];
    }
}

// ---------------------------------------------------------------------------
// K2a: one block per (side,bucket): scan nblk per-block counts -> bases+total
// ---------------------------------------------------------------------------
__global__ void scan_blocks_kernel(const int* __restrict__ cnt_col, const int* __restrict__ cnt_row,
                                   int* __restrict__ base_col, int* __restrict__ base_row,
                                   int* __restrict__ tot_col, int* __restrict__ tot_row,
                                   int nblk, int nb) {
    __shared__ int s[256];
    int side = (blockIdx.x >= (unsigned)nb) ? 1 : 0;
    int b = blockIdx.x - side * nb;
    const int* cnt = side ? cnt_row : cnt_col;
    int* base = side ? base_row : base_col;
    int* tot  = side ? tot_row  : tot_col;
    int t = threadIdx.x;
    int v = (t < nblk) ? cnt[(size_t)t * nb + b] : 0;
    s[t] = v;
    __syncthreads();
    for (int off = 1; off < 256; off <<= 1) {
        int u = (t >= off) ? s[t - off] : 0;
        __syncthreads();
        s[t] += u;
        __syncthreads();
    }
    if (t < nblk) base[(size_t)t * nb + b] = s[t] - v;
    if (t == 255) tot[b] = s[255];
}

// ---------------------------------------------------------------------------
// K2c (fused with old K2b): each (side,bucket) block re-derives its bucket
// base by scanning the totals array in LDS, then adds into per-block bases.
// Also emits bb_col/bb_row (used by deg/csr kernels) and row_ptr[n] = e.
// ---------------------------------------------------------------------------
__global__ void add_bases_kernel(int* __restrict__ base_col, int* __restrict__ base_row,
                                 const int* __restrict__ tot_col, const int* __restrict__ tot_row,
                                 int* __restrict__ bb_col, int* __restrict__ bb_row,
                                 int* __restrict__ row_ptr, int n, int e, int nblk, int nb) {
    __shared__ int s[256];
    __shared__ int bbv;
    int side = (blockIdx.x >= (unsigned)nb) ? 1 : 0;
    int b = blockIdx.x - side * nb;
    const int* tot = side ? tot_row : tot_col;
    int* base = side ? base_row : base_col;
    int t = threadIdx.x;
    int v = (t < nb) ? tot[t] : 0;
    s[t] = v;
    __syncthreads();
    for (int off = 1; off < 256; off <<= 1) {
        int u = (t >= off) ? s[t - off] : 0;
        __syncthreads();
        s[t] += u;
        __syncthreads();
    }
    if (t == 0) {
        bbv = (b > 0) ? s[b - 1] : 0;
        (side ? bb_row : bb_col)[b] = bbv;
    }
    __syncthreads();
    int add = bbv;
    for (int j = t; j < nblk; j += blockDim.x) base[(size_t)j * nb + b] += add;
    if (blockIdx.x == 0 && t == 0) row_ptr[n] = e;
}

// ---------------------------------------------------------------------------
// K3: scatter edges into bucket-major temps via LDS cursors (512 threads)
// ---------------------------------------------------------------------------
__global__ void part_scatter_kernel(const int* __restrict__ row, const int* __restrict__ col,
                                    const float* __restrict__ ppmi,
                                    const int* __restrict__ base_col, const int* __restrict__ base_row,
                                    int4* __restrict__ tmp_col, int2* __restrict__ tmp_row,
                                    int e, int nb) {
    __shared__ int cc[256], cr[256];
    int t = threadIdx.x;
    if (t < nb) {
        cc[t] = base_col[blockIdx.x * nb + t];
        cr[t] = base_row[blockIdx.x * nb + t];
    }
    __syncthreads();
    int base = blockIdx.x * EPB;
    int lim  = min(EPB, e - base);
    for (int i = t; i < lim; i += 512) {
        int r = row[base + i], c = col[base + i];
        int w = __float_as_int(ppmi[base + i]);
        int sc = atomicAdd(&cc[c >> 9], 1);
        tmp_col[sc] = make_int4(c, r, w, 0);
        int sr = atomicAdd(&cr[r >> 9], 1);
        tmp_row[sr] = make_int2(r, w);
    }
}

// ---------------------------------------------------------------------------
// K4b: per-row-bucket degree accumulation in LDS -> dis (float2: {g, p})
// 512 threads: one thread per bucket slot.
// ---------------------------------------------------------------------------
__global__ void deg_bucket_kernel(const int2* __restrict__ tmp_row,
                                  const int* __restrict__ bb_row, const int* __restrict__ tot_row,
                                  float2* __restrict__ dis, int n) {
    __shared__ float dg[BKT], dp[BKT];
    int t = threadIdx.x;   // 512
    dg[t] = 1.0f; dp[t] = 1.0f;   // self-loop
    __syncthreads();
    int b = blockIdx.x;
    int beg = bb_row[b], cnt = tot_row[b];
    for (int i = t; i < cnt; i += 512) {
        int2 cell = tmp_row[beg + i];
        int lr = cell.x & (BKT - 1);
        atomicAdd(&dg[lr], 1.0f);
        atomicAdd(&dp[lr], __int_as_float(cell.y));
    }
    __syncthreads();
    int g = (b << 9) + t;
    if (g < n) dis[g] = make_float2(rsqrtf(dg[t]), rsqrtf(dp[t]));
}

// ---------------------------------------------------------------------------
// K4: per-col-bucket CSR finalize -> packed edge meta {src, wg, wp, 0}
// ---------------------------------------------------------------------------
__launch_bounds__(512)
__global__ void csr_bucket_kernel(const int4* __restrict__ tmp_col,
                                  const int* __restrict__ bb_col, const int* __restrict__ tot_col,
                                  const float2* __restrict__ dis,
                                  int* __restrict__ row_ptr, int4* __restrict__ csr_meta, int n) {
    __shared__ int hist[BKT], s[BKT], cur[BKT];
    int t = threadIdx.x;   // 512 threads
    hist[t] = 0;
    __syncthreads();
    int b = blockIdx.x;
    int beg = bb_col[b], cnt = tot_col[b];
    for (int i = t; i < cnt; i += BKT) atomicAdd(&hist[tmp_col[beg + i].x & (BKT - 1)], 1);
    __syncthreads();
    int own = hist[t];
    s[t] = own;
    __syncthreads();
    for (int off = 1; off < BKT; off <<= 1) {
        int v = (t >= off) ? s[t - off] : 0;
        __syncthreads();
        s[t] += v;
        __syncthreads();
    }
    int gslot = beg + s[t] - own;
    cur[t] = gslot;
    int gc = (b << 9) + t;
    if (gc < n) row_ptr[gc] = gslot;
    __syncthreads();
    for (int i = t; i < cnt; i += BKT) {
        int4 cell = tmp_col[beg + i];
        int lc = cell.x & (BKT - 1);
        int slot = atomicAdd(&cur[lc], 1);
        int r = cell.y;
        float w = __int_as_float(cell.z);
        float2 d = dis[r];
        csr_meta[slot] = make_int4(r, __float_as_int(d.x), __float_as_int(d.y * w), 0);
    }
}

// ---------------------------------------------------------------------------
// W -> B^T split-bf16 prep
// ---------------------------------------------------------------------------
__global__ void conv_w_kernel(const float* __restrict__ W, __bf16* __restrict__ Bh,
                              __bf16* __restrict__ Bl, int K, int N) {
    int i = blockIdx.x * blockDim.x + threadIdx.x;
    if (i >= K * N) return;
    int k = i / N, nn = i % N;
    float v = W[i];
    __bf16 h = (__bf16)v;
    Bh[(size_t)nn * K + k] = h;
    Bl[(size_t)nn * K + k] = (__bf16)(v - (float)h);
}

// ---------------------------------------------------------------------------
// Split-bf16 MFMA GEMM: C[M,BN] = A[M,K] @ B[K,BN]; OT = fp32 or bf16 output.
// ILV: interleave rows [0,nHalf) and [nHalf,2*nHalf) as C[c][col][{0,1}].
// ---------------------------------------------------------------------------
template<int BM, int BN, typename OT, bool ILV>
__launch_bounds__(256, 2)
__global__ void mfma_gemm_kernel(const float* __restrict__ A,
                                 const __bf16* __restrict__ Bth, const __bf16* __restrict__ Btl,
                                 OT* __restrict__ C, int M, int K, int nHalf) {
    constexpr int BK  = 32;
    constexpr int LDK = BK + 8;
    constexpr int WM  = BM / 4;
    constexpr int MT  = WM / 16;
    constexpr int NT  = BN / 16;
    __shared__ __bf16 Ash[BM * LDK];
    __shared__ __bf16 Asl[BM * LDK];
    __shared__ __bf16 Bsh[BN * LDK];
    __shared__ __bf16 Bsl[BN * LDK];

    const int tid  = threadIdx.x;
    const int wave = tid >> 6;
    const int lane = tid & 63;
    const int quad = lane >> 4;
    const int l16  = lane & 15;
    const int row0 = blockIdx.x * BM;

    f32x4 acc[MT][NT] = {};

    for (int k0 = 0; k0 < K; k0 += BK) {
#pragma unroll
        for (int p = 0; p < BM / 32; ++p) {
            int lin = p * 256 + tid;
            int r   = lin >> 3;
            int kc  = (lin & 7) * 4;
            int gr  = row0 + r;
            float4 v;
            if (gr < M) v = *(const float4*)(A + (size_t)gr * K + k0 + kc);
            else        v = make_float4(0.f, 0.f, 0.f, 0.f);
            __bf16 h0 = (__bf16)v.x, h1 = (__bf16)v.y, h2 = (__bf16)v.z, h3 = (__bf16)v.w;
            __bf16 l0 = (__bf16)(v.x - (float)h0), l1 = (__bf16)(v.y - (float)h1);
            __bf16 l2 = (__bf16)(v.z - (float)h2), l3 = (__bf16)(v.w - (float)h3);
            *(bf16x4*)&Ash[r * LDK + kc] = (bf16x4){h0, h1, h2, h3};
            *(bf16x4*)&Asl[r * LDK + kc] = (bf16x4){l0, l1, l2, l3};
        }
#pragma unroll
        for (int p = 0; p < BN / 64; ++p) {
            int lin = p * 256 + tid;
            int r   = lin >> 2;
            int kc  = (lin & 3) * 8;
            *(uint4*)&Bsh[r * LDK + kc] = *(const uint4*)(Bth + (size_t)r * K + k0 + kc);
            *(uint4*)&Bsl[r * LDK + kc] = *(const uint4*)(Btl + (size_t)r * K + k0 + kc);
        }
        __syncthreads();

        bf16x8 bh[NT], bl[NT];
#pragma unroll
        for (int j = 0; j < NT; ++j) {
            bh[j] = *(const bf16x8*)&Bsh[(j * 16 + l16) * LDK + quad * 8];
            bl[j] = *(const bf16x8*)&Bsl[(j * 16 + l16) * LDK + quad * 8];
        }
#pragma unroll
        for (int i = 0; i < MT; ++i) {
            int m = wave * WM + i * 16 + l16;
            bf16x8 ah = *(const bf16x8*)&Ash[m * LDK + quad * 8];
            bf16x8 al = *(const bf16x8*)&Asl[m * LDK + quad * 8];
#pragma unroll
            for (int j = 0; j < NT; ++j) {
                acc[i][j] = __builtin_amdgcn_mfma_f32_16x16x32_bf16(ah, bh[j], acc[i][j], 0, 0, 0);
                acc[i][j] = __builtin_amdgcn_mfma_f32_16x16x32_bf16(ah, bl[j], acc[i][j], 0, 0, 0);
                acc[i][j] = __builtin_amdgcn_mfma_f32_16x16x32_bf16(al, bh[j], acc[i][j], 0, 0, 0);
            }
        }
        __syncthreads();
    }

#pragma unroll
    for (int i = 0; i < MT; ++i) {
#pragma unroll
        for (int rg = 0; rg < 4; ++rg) {
            int gr = row0 + wave * WM + i * 16 + quad * 4 + rg;
            if (gr < M) {
                if constexpr (ILV) {
                    int s = (gr >= nHalf) ? 1 : 0;
                    size_t base = (size_t)(gr - s * nHalf) * (BN * 2) + s;
#pragma unroll
                    for (int j = 0; j < NT; ++j)
                        C[base + (size_t)(j * 16 + l16) * 2] = (OT)acc[i][j][rg];
                } else {
#pragma unroll
                    for (int j = 0; j < NT; ++j)
                        C[(size_t)gr * BN + j * 16 + l16] = (OT)acc[i][j][rg];
                }
            }
        }
    }
}

// ---------------------------------------------------------------------------
// Layer-1 pull aggregation: one wave per node; R1 structure, unroll 8 + 4 + 1
// (no predication waste; deeper in-flight gather window).
// ---------------------------------------------------------------------------
__global__ void agg1_pull_kernel(const int* __restrict__ row_ptr, const int4* __restrict__ meta,
                                 const __bf16* __restrict__ hw1,
                                 const float2* __restrict__ dis,
                                 const float* __restrict__ b1,
                                 float* __restrict__ g_out, float* __restrict__ p_out, int n) {
    int c    = blockIdx.x * 4 + (threadIdx.x >> 6);
    int lane = threadIdx.x & 63;
    if (c >= n) return;
    int beg = row_ptr[c], end = row_ptr[c + 1];
    int f2 = lane * 2;
    float sgx = 0.f, sgy = 0.f, spx = 0.f, spy = 0.f;
    int t = beg;
    for (; t + 8 <= end; t += 8) {
        int4 m[8];
#pragma unroll
        for (int q = 0; q < 8; ++q) m[q] = meta[t + q];
        unsigned u[8];
#pragma unroll
        for (int q = 0; q < 8; ++q)
            u[q] = *(const unsigned*)(hw1 + ((size_t)m[q].x << 7) + f2);
#pragma unroll
        for (int q = 0; q < 8; ++q) {
            float2 h = bf2_to_f2(u[q]);
            float wg = __int_as_float(m[q].y), wp = __int_as_float(m[q].z);
            sgx += wg * h.x; sgy += wg * h.y;
            spx += wp * h.x; spy += wp * h.y;
        }
    }
    if (t + 4 <= end) {
        int4 m[4];
#pragma unroll
        for (int q = 0; q < 4; ++q) m[q] = meta[t + q];
        unsigned u[4];
#pragma unroll
        for (int q = 0; q < 4; ++q)
            u[q] = *(const unsigned*)(hw1 + ((size_t)m[q].x << 7) + f2);
#pragma unroll
        for (int q = 0; q < 4; ++q) {
            float2 h = bf2_to_f2(u[q]);
            float wg = __int_as_float(m[q].y), wp = __int_as_float(m[q].z);
            sgx += wg * h.x; sgy += wg * h.y;
            spx += wp * h.x; spy += wp * h.y;
        }
        t += 4;
    }
    for (; t < end; ++t) {
        int4 m0 = meta[t];
        float2 h0 = bf2_to_f2(*(const unsigned*)(hw1 + ((size_t)m0.x << 7) + f2));
        float wg0 = __int_as_float(m0.y), wp0 = __int_as_float(m0.z);
        sgx += wg0 * h0.x; sgy += wg0 * h0.y;
        spx += wp0 * h0.x; spy += wp0 * h0.y;
    }
    float2 d = dis[c];
    size_t idx = ((size_t)c << 7) + f2;
    float2 hs = bf2_to_f2(*(const unsigned*)(hw1 + idx));
    float2 bv = *(const float2*)(b1 + f2);
    float gx = d.x * sgx + d.x * d.x * hs.x + bv.x;
    float gy = d.x * sgy + d.x * d.x * hs.y + bv.y;
    float px = d.y * spx + d.y * d.y * hs.x + bv.x;
    float py = d.y * spy + d.y * d.y * hs.y + bv.y;
    float2 go, po;
    go.x = gx > 0.f ? gx : 0.f;  go.y = gy > 0.f ? gy : 0.f;
    po.x = px > 0.f ? px : 0.f;  po.y = py > 0.f ? py : 0.f;
    *(float2*)&g_out[idx] = go;
    *(float2*)&p_out[idx] = po;
}

// ---------------------------------------------------------------------------
// Layer-2 pull aggregation + self-loop + bias + softmax gate.
// hw2i layout: [n][64][2] bf16, (g,p) adjacent -> one dword gather per edge.
// R1 structure, unroll 8 + 4 + 1.
// ---------------------------------------------------------------------------
__global__ void agg2_final_kernel(const int* __restrict__ row_ptr, const int4* __restrict__ meta,
                                  const __bf16* __restrict__ hw2i,
                                  const float2* __restrict__ dis,
                                  const float* __restrict__ b2,
                                  const float* __restrict__ dense_w, const float* __restrict__ dense_b,
                                  float* __restrict__ out, int n) {
    int c = blockIdx.x * 4 + (threadIdx.x >> 6);
    int f = threadIdx.x & 63;
    if (c >= n) return;
    int beg = row_ptr[c], end = row_ptr[c + 1];
    int f2 = f * 2;
    float sg = 0.f, sp = 0.f;
    int t = beg;
    for (; t + 8 <= end; t += 8) {
        int4 m[8];
#pragma unroll
        for (int q = 0; q < 8; ++q) m[q] = meta[t + q];
        unsigned u[8];
#pragma unroll
        for (int q = 0; q < 8; ++q)
            u[q] = *(const unsigned*)(hw2i + ((size_t)m[q].x << 7) + f2);
#pragma unroll
        for (int q = 0; q < 8; ++q) {
            float2 g0 = bf2_to_f2(u[q]);
            sg += __int_as_float(m[q].y) * g0.x;
            sp += __int_as_float(m[q].z) * g0.y;
        }
    }
    if (t + 4 <= end) {
        int4 m[4];
#pragma unroll
        for (int q = 0; q < 4; ++q) m[q] = meta[t + q];
        unsigned u[4];
#pragma unroll
        for (int q = 0; q < 4; ++q)
            u[q] = *(const unsigned*)(hw2i + ((size_t)m[q].x << 7) + f2);
#pragma unroll
        for (int q = 0; q < 4; ++q) {
            float2 g0 = bf2_to_f2(u[q]);
            sg += __int_as_float(m[q].y) * g0.x;
            sp += __int_as_float(m[q].z) * g0.y;
        }
        t += 4;
    }
    for (; t < end; ++t) {
        int4 m0 = meta[t];
        float2 g0 = bf2_to_f2(*(const unsigned*)(hw2i + ((size_t)m0.x << 7) + f2));
        sg += __int_as_float(m0.y) * g0.x;
        sp += __int_as_float(m0.z) * g0.y;
    }
    float2 d = dis[c];
    float2 gps = bf2_to_f2(*(const unsigned*)(hw2i + ((size_t)c << 7) + f2));
    float bb = b2[f];
    float gv = d.x * sg + d.x * d.x * gps.x + bb;
    float pv = d.y * sp + d.y * d.y * gps.y + bb;
    float dwv = dense_w[f];
    float lg = gv * dwv, lp = pv * dwv;
#pragma unroll
    for (int off = 32; off > 0; off >>= 1) {
        lg += __shfl_xor(lg, off, 64);
        lp += __shfl_xor(lp, off, 64);
    }
    lg += dense_b[0];
    lp += dense_b[0];
    float m  = fmaxf(lg, lp);
    float eg = expf(lg - m), ep = expf(lp - m);
    float wgt = eg / (eg + ep);
    out[(size_t)c * OO + f] = wgt * gv + (1.0f - wgt) * pv;
}

// ---------------------------------------------------------------------------
extern "C" void kernel_launch(void* const* d_in, const int* in_sizes, int n_in,
                              void* d_out, int out_size, void* d_ws, size_t ws_size,
                              hipStream_t stream) {
    const float* x    = (const float*)d_in[0];
    const int*   ei   = (const int*)d_in[1];
    const float* ppmi = (const float*)d_in[2];
    const float* W1   = (const float*)d_in[3];
    const float* b1   = (const float*)d_in[4];
    const float* W2   = (const float*)d_in[5];
    const float* b2   = (const float*)d_in[6];
    const float* dw   = (const float*)d_in[7];
    const float* db   = (const float*)d_in[8];
    float* out = (float*)d_out;

    const int n = in_sizes[0] / DD;       // 100000
    const int e = in_sizes[2];            // 1600000
    const int* row = ei;
    const int* col = ei + e;

    const int nb   = (n + BKT - 1) / BKT;   // buckets (<=256 required)
    const int nblk = (e + EPB - 1) / EPB;   // partition blocks (<=256 required)

    // ---- workspace layout ----
    float* ws      = (float*)d_ws;
    float2* dis    = (float2*)ws;                     // n float2
    __bf16* hw1    = (__bf16*)(ws + 2 * (size_t)n);   // n*128 bf16 (aliased as hw2i [n][64][2])
    float* g1      = (float*)(hw1 + (size_t)n * HH);  // n*128 f32 (tmp_col aliases: int4[e])
    float* p1      = g1 + (size_t)n * HH;             // n*128 f32 (tmp_row aliases: int2[e])
    int4* csr_meta = (int4*)(p1 + (size_t)n * HH);    // e int4 {src, wg, wp, 0}
    __bf16* bt1h   = (__bf16*)(csr_meta + e);         // DD*HH
    __bf16* bt1l   = bt1h + (size_t)DD * HH;
    __bf16* bt2h   = bt1l + (size_t)DD * HH;          // HH*OO
    __bf16* bt2l   = bt2h + (size_t)HH * OO;
    int* row_ptr   = (int*)(bt2l + (size_t)HH * OO);  // n+1
    int* cnt_col   = row_ptr + (n + 1);               // nblk*nb
    int* base_col  = cnt_col + (size_t)nblk * nb;     // nblk*nb
    int* cnt_row   = base_col + (size_t)nblk * nb;    // nblk*nb
    int* base_row  = cnt_row + (size_t)nblk * nb;     // nblk*nb
    int* bb_col    = base_row + (size_t)nblk * nb;    // nb
    int* tot_col   = bb_col + nb;                     // nb
    int* bb_row    = tot_col + nb;                    // nb
    int* tot_row   = bb_row + nb;                     // nb
    int4* tmp_col  = (int4*)g1;                       // e (alias, dead before agg1 writes g1)
    int2* tmp_row  = (int2*)p1;                       // e (alias, dead before agg1 writes p1)
    __bf16* hw2i   = hw1;                             // [n][64][2] bf16 (hw1 dead after agg1)

    const int T = 256;

    // ---- partition pipeline (LDS atomics only, fully parallel scans) ----
    part_count_kernel<<<nblk, 512, 0, stream>>>(row, col, e, nb, cnt_col, cnt_row);
    scan_blocks_kernel<<<2 * nb, T, 0, stream>>>(cnt_col, cnt_row, base_col, base_row,
                                                 tot_col, tot_row, nblk, nb);
    add_bases_kernel<<<2 * nb, T, 0, stream>>>(base_col, base_row, tot_col, tot_row,
                                               bb_col, bb_row, row_ptr, n, e, nblk, nb);
    part_scatter_kernel<<<nblk, 512, 0, stream>>>(row, col, ppmi, base_col, base_row,
                                                  tmp_col, tmp_row, e, nb);
    deg_bucket_kernel<<<nb, 512, 0, stream>>>(tmp_row, bb_row, tot_row, dis, n);
    csr_bucket_kernel<<<nb, BKT, 0, stream>>>(tmp_col, bb_col, tot_col, dis,
                                              row_ptr, csr_meta, n);

    // ---- weight prep ----
    conv_w_kernel<<<(DD * HH + T - 1) / T, T, 0, stream>>>(W1, bt1h, bt1l, DD, HH);
    conv_w_kernel<<<(HH * OO + T - 1) / T, T, 0, stream>>>(W2, bt2h, bt2l, HH, OO);

    // ---- network ----
    mfma_gemm_kernel<128, HH, __bf16, false><<<(n + 127) / 128, 256, 0, stream>>>(
        x, bt1h, bt1l, hw1, n, DD, 0);
    agg1_pull_kernel<<<(n + 3) / 4, 256, 0, stream>>>(row_ptr, csr_meta, hw1, dis, b1, g1, p1, n);
    mfma_gemm_kernel<128, OO, __bf16, true><<<(2 * n + 127) / 128, 256, 0, stream>>>(
        g1, bt2h, bt2l, hw2i, 2 * n, HH, n);
    agg2_final_kernel<<<(n + 3) / 4, 256, 0, stream>>>(row_ptr, csr_meta, hw2i, dis,
                                                       b2, dw, db, out, n);
}

// Round 4
// 512.797 us; speedup vs baseline: 1.1041x; 1.0235x over previous
//
#include <hip/hip_runtime.h>
#include <hip/hip_bf16.h>
#include <math.h>

#define DD 256
#define HH 128
#define OO 64

#define EPB 8192          // edges per partition block
#define BKT 512           // nodes per bucket (bucket = idx >> 9)
#define AWIN 512          // agg LDS meta window (edges)

typedef __attribute__((ext_vector_type(8))) __bf16 bf16x8;
typedef __attribute__((ext_vector_type(4))) __bf16 bf16x4;
typedef __attribute__((ext_vector_type(4))) float f32x4;
typedef __attribute__((ext_vector_type(2))) float f32x2;
typedef __attribute__((ext_vector_type(4))) int i32x4;

__device__ inline float2 bf2_to_f2(unsigned u) {
    float2 r;
    r.x = __uint_as_float(u << 16);
    r.y = __uint_as_float(u & 0xffff0000u);
    return r;
}

// ---------------------------------------------------------------------------
// K1: per-block LDS histograms over coarse buckets (both col and row sides)
// ---------------------------------------------------------------------------
__global__ void part_count_kernel(const int* __restrict__ row, const int* __restrict__ col,
                                  int e, int nb,
                                  int* __restrict__ cnt_col, int* __restrict__ cnt_row) {
    __shared__ int hc[256], hr[256];
    int t = threadIdx.x;
    if (t < 256) { hc[t] = 0; hr[t] = 0; }
    __syncthreads();
    int base = blockIdx.x * EPB;
    int lim  = min(EPB, e - base);
    for (int i = t; i < lim; i += 512) {
        atomicAdd(&hc[col[base + i] >> 9], 1);
        atomicAdd(&hr[row[base + i] >> 9], 1);
    }
    __syncthreads();
    if (t < nb) {
        cnt_col[blockIdx.x * nb + t] = hc[t];
        cnt_row[blockIdx.x * nb + t] = hr[t];
    }
}

// ---------------------------------------------------------------------------
// K2a: one block per (side,bucket): scan nblk per-block counts -> bases+total
// ---------------------------------------------------------------------------
__global__ void scan_blocks_kernel(const int* __restrict__ cnt_col, const int* __restrict__ cnt_row,
                                   int* __restrict__ base_col, int* __restrict__ base_row,
                                   int* __restrict__ tot_col, int* __restrict__ tot_row,
                                   int nblk, int nb) {
    __shared__ int s[256];
    int side = (blockIdx.x >= (unsigned)nb) ? 1 : 0;
    int b = blockIdx.x - side * nb;
    const int* cnt = side ? cnt_row : cnt_col;
    int* base = side ? base_row : base_col;
    int* tot  = side ? tot_row  : tot_col;
    int t = threadIdx.x;
    int v = (t < nblk) ? cnt[(size_t)t * nb + b] : 0;
    s[t] = v;
    __syncthreads();
    for (int off = 1; off < 256; off <<= 1) {
        int u = (t >= off) ? s[t - off] : 0;
        __syncthreads();
        s[t] += u;
        __syncthreads();
    }
    if (t < nblk) base[(size_t)t * nb + b] = s[t] - v;
    if (t == 255) tot[b] = s[255];
}

// ---------------------------------------------------------------------------
// K2c: each (side,bucket) block re-derives its bucket base from totals in LDS,
// adds into per-block bases; emits bb_col/bb_row and row_ptr[n] = e.
// ---------------------------------------------------------------------------
__global__ void add_bases_kernel(int* __restrict__ base_col, int* __restrict__ base_row,
                                 const int* __restrict__ tot_col, const int* __restrict__ tot_row,
                                 int* __restrict__ bb_col, int* __restrict__ bb_row,
                                 int* __restrict__ row_ptr, int n, int e, int nblk, int nb) {
    __shared__ int s[256];
    __shared__ int bbv;
    int side = (blockIdx.x >= (unsigned)nb) ? 1 : 0;
    int b = blockIdx.x - side * nb;
    const int* tot = side ? tot_row : tot_col;
    int* base = side ? base_row : base_col;
    int t = threadIdx.x;
    int v = (t < nb) ? tot[t] : 0;
    s[t] = v;
    __syncthreads();
    for (int off = 1; off < 256; off <<= 1) {
        int u = (t >= off) ? s[t - off] : 0;
        __syncthreads();
        s[t] += u;
        __syncthreads();
    }
    if (t == 0) {
        bbv = (b > 0) ? s[b - 1] : 0;
        (side ? bb_row : bb_col)[b] = bbv;
    }
    __syncthreads();
    int add = bbv;
    for (int j = t; j < nblk; j += blockDim.x) base[(size_t)j * nb + b] += add;
    if (blockIdx.x == 0 && t == 0) row_ptr[n] = e;
}

// ---------------------------------------------------------------------------
// K3: scatter edges into bucket-major temps via LDS cursors (512 threads)
// ---------------------------------------------------------------------------
__global__ void part_scatter_kernel(const int* __restrict__ row, const int* __restrict__ col,
                                    const float* __restrict__ ppmi,
                                    const int* __restrict__ base_col, const int* __restrict__ base_row,
                                    int4* __restrict__ tmp_col, int2* __restrict__ tmp_row,
                                    int e, int nb) {
    __shared__ int cc[256], cr[256];
    int t = threadIdx.x;
    if (t < nb) {
        cc[t] = base_col[blockIdx.x * nb + t];
        cr[t] = base_row[blockIdx.x * nb + t];
    }
    __syncthreads();
    int base = blockIdx.x * EPB;
    int lim  = min(EPB, e - base);
    for (int i = t; i < lim; i += 512) {
        int r = row[base + i], c = col[base + i];
        int w = __float_as_int(ppmi[base + i]);
        int sc = atomicAdd(&cc[c >> 9], 1);
        tmp_col[sc] = make_int4(c, r, w, 0);
        int sr = atomicAdd(&cr[r >> 9], 1);
        tmp_row[sr] = make_int2(r, w);
    }
}

// ---------------------------------------------------------------------------
// K4b: per-row-bucket degree accumulation in LDS -> dis (float2: {g, p})
// ---------------------------------------------------------------------------
__global__ void deg_bucket_kernel(const int2* __restrict__ tmp_row,
                                  const int* __restrict__ bb_row, const int* __restrict__ tot_row,
                                  float2* __restrict__ dis, int n) {
    __shared__ float dg[BKT], dp[BKT];
    int t = threadIdx.x;   // 512
    dg[t] = 1.0f; dp[t] = 1.0f;   // self-loop
    __syncthreads();
    int b = blockIdx.x;
    int beg = bb_row[b], cnt = tot_row[b];
    for (int i = t; i < cnt; i += 512) {
        int2 cell = tmp_row[beg + i];
        int lr = cell.x & (BKT - 1);
        atomicAdd(&dg[lr], 1.0f);
        atomicAdd(&dp[lr], __int_as_float(cell.y));
    }
    __syncthreads();
    int g = (b << 9) + t;
    if (g < n) dis[g] = make_float2(rsqrtf(dg[t]), rsqrtf(dp[t]));
}

// ---------------------------------------------------------------------------
// K4: per-col-bucket CSR finalize -> packed edge meta {src, wg, wp, 0}
// ---------------------------------------------------------------------------
__launch_bounds__(512)
__global__ void csr_bucket_kernel(const int4* __restrict__ tmp_col,
                                  const int* __restrict__ bb_col, const int* __restrict__ tot_col,
                                  const float2* __restrict__ dis,
                                  int* __restrict__ row_ptr, int4* __restrict__ csr_meta, int n) {
    __shared__ int hist[BKT], s[BKT], cur[BKT];
    int t = threadIdx.x;   // 512 threads
    hist[t] = 0;
    __syncthreads();
    int b = blockIdx.x;
    int beg = bb_col[b], cnt = tot_col[b];
    for (int i = t; i < cnt; i += BKT) atomicAdd(&hist[tmp_col[beg + i].x & (BKT - 1)], 1);
    __syncthreads();
    int own = hist[t];
    s[t] = own;
    __syncthreads();
    for (int off = 1; off < BKT; off <<= 1) {
        int v = (t >= off) ? s[t - off] : 0;
        __syncthreads();
        s[t] += v;
        __syncthreads();
    }
    int gslot = beg + s[t] - own;
    cur[t] = gslot;
    int gc = (b << 9) + t;
    if (gc < n) row_ptr[gc] = gslot;
    __syncthreads();
    for (int i = t; i < cnt; i += BKT) {
        int4 cell = tmp_col[beg + i];
        int lc = cell.x & (BKT - 1);
        int slot = atomicAdd(&cur[lc], 1);
        int r = cell.y;
        float w = __int_as_float(cell.z);
        float2 d = dis[r];
        csr_meta[slot] = make_int4(r, __float_as_int(d.x), __float_as_int(d.y * w), 0);
    }
}

// ---------------------------------------------------------------------------
// W -> B^T split-bf16 prep
// ---------------------------------------------------------------------------
__global__ void conv_w_kernel(const float* __restrict__ W, __bf16* __restrict__ Bh,
                              __bf16* __restrict__ Bl, int K, int N) {
    int i = blockIdx.x * blockDim.x + threadIdx.x;
    if (i >= K * N) return;
    int k = i / N, nn = i % N;
    float v = W[i];
    __bf16 h = (__bf16)v;
    Bh[(size_t)nn * K + k] = h;
    Bl[(size_t)nn * K + k] = (__bf16)(v - (float)h);
}

// ---------------------------------------------------------------------------
// Split-bf16 MFMA GEMM: C[M,BN] = A[M,K] @ B[K,BN]; OT = fp32 or bf16 output.
// ILV: interleave rows [0,nHalf) and [nHalf,2*nHalf) as C[c][col][{0,1}].
// ---------------------------------------------------------------------------
template<int BM, int BN, typename OT, bool ILV>
__launch_bounds__(256, 2)
__global__ void mfma_gemm_kernel(const float* __restrict__ A,
                                 const __bf16* __restrict__ Bth, const __bf16* __restrict__ Btl,
                                 OT* __restrict__ C, int M, int K, int nHalf) {
    constexpr int BK  = 32;
    constexpr int LDK = BK + 8;
    constexpr int WM  = BM / 4;
    constexpr int MT  = WM / 16;
    constexpr int NT  = BN / 16;
    __shared__ __bf16 Ash[BM * LDK];
    __shared__ __bf16 Asl[BM * LDK];
    __shared__ __bf16 Bsh[BN * LDK];
    __shared__ __bf16 Bsl[BN * LDK];

    const int tid  = threadIdx.x;
    const int wave = tid >> 6;
    const int lane = tid & 63;
    const int quad = lane >> 4;
    const int l16  = lane & 15;
    const int row0 = blockIdx.x * BM;

    f32x4 acc[MT][NT] = {};

    for (int k0 = 0; k0 < K; k0 += BK) {
#pragma unroll
        for (int p = 0; p < BM / 32; ++p) {
            int lin = p * 256 + tid;
            int r   = lin >> 3;
            int kc  = (lin & 7) * 4;
            int gr  = row0 + r;
            float4 v;
            if (gr < M) v = *(const float4*)(A + (size_t)gr * K + k0 + kc);
            else        v = make_float4(0.f, 0.f, 0.f, 0.f);
            __bf16 h0 = (__bf16)v.x, h1 = (__bf16)v.y, h2 = (__bf16)v.z, h3 = (__bf16)v.w;
            __bf16 l0 = (__bf16)(v.x - (float)h0), l1 = (__bf16)(v.y - (float)h1);
            __bf16 l2 = (__bf16)(v.z - (float)h2), l3 = (__bf16)(v.w - (float)h3);
            *(bf16x4*)&Ash[r * LDK + kc] = (bf16x4){h0, h1, h2, h3};
            *(bf16x4*)&Asl[r * LDK + kc] = (bf16x4){l0, l1, l2, l3};
        }
#pragma unroll
        for (int p = 0; p < BN / 64; ++p) {
            int lin = p * 256 + tid;
            int r   = lin >> 2;
            int kc  = (lin & 3) * 8;
            *(uint4*)&Bsh[r * LDK + kc] = *(const uint4*)(Bth + (size_t)r * K + k0 + kc);
            *(uint4*)&Bsl[r * LDK + kc] = *(const uint4*)(Btl + (size_t)r * K + k0 + kc);
        }
        __syncthreads();

        bf16x8 bh[NT], bl[NT];
#pragma unroll
        for (int j = 0; j < NT; ++j) {
            bh[j] = *(const bf16x8*)&Bsh[(j * 16 + l16) * LDK + quad * 8];
            bl[j] = *(const bf16x8*)&Bsl[(j * 16 + l16) * LDK + quad * 8];
        }
#pragma unroll
        for (int i = 0; i < MT; ++i) {
            int m = wave * WM + i * 16 + l16;
            bf16x8 ah = *(const bf16x8*)&Ash[m * LDK + quad * 8];
            bf16x8 al = *(const bf16x8*)&Asl[m * LDK + quad * 8];
#pragma unroll
            for (int j = 0; j < NT; ++j) {
                acc[i][j] = __builtin_amdgcn_mfma_f32_16x16x32_bf16(ah, bh[j], acc[i][j], 0, 0, 0);
                acc[i][j] = __builtin_amdgcn_mfma_f32_16x16x32_bf16(ah, bl[j], acc[i][j], 0, 0, 0);
                acc[i][j] = __builtin_amdgcn_mfma_f32_16x16x32_bf16(al, bh[j], acc[i][j], 0, 0, 0);
            }
        }
        __syncthreads();
    }

#pragma unroll
    for (int i = 0; i < MT; ++i) {
#pragma unroll
        for (int rg = 0; rg < 4; ++rg) {
            int gr = row0 + wave * WM + i * 16 + quad * 4 + rg;
            if (gr < M) {
                if constexpr (ILV) {
                    int s = (gr >= nHalf) ? 1 : 0;
                    size_t base = (size_t)(gr - s * nHalf) * (BN * 2) + s;
#pragma unroll
                    for (int j = 0; j < NT; ++j)
                        C[base + (size_t)(j * 16 + l16) * 2] = (OT)acc[i][j][rg];
                } else {
#pragma unroll
                    for (int j = 0; j < NT; ++j)
                        C[(size_t)gr * BN + j * 16 + l16] = (OT)acc[i][j][rg];
                }
            }
        }
    }
}

// ---------------------------------------------------------------------------
// Layer-1 pull aggregation: one wave per node. Block's 4 nodes share a
// contiguous meta range -> cooperative nontemporal load into LDS (windowed),
// inner loop reads meta via LDS broadcast; only gathers hit global.
// ---------------------------------------------------------------------------
__global__ void agg1_pull_kernel(const int* __restrict__ row_ptr, const int4* __restrict__ meta,
                                 const __bf16* __restrict__ hw1,
                                 const float2* __restrict__ dis,
                                 const float* __restrict__ b1,
                                 float* __restrict__ g_out, float* __restrict__ p_out, int n) {
    __shared__ i32x4 sm[AWIN];
    const int tid  = threadIdx.x;
    const int wave = tid >> 6;
    const int lane = tid & 63;
    const int c0   = blockIdx.x * 4;
    const int c    = c0 + wave;
    const int beg0 = row_ptr[c0];
    const int end3 = row_ptr[min(c0 + 4, n)];
    int beg = 0, end = 0;
    if (c < n) { beg = row_ptr[c]; end = row_ptr[c + 1]; }
    const int f2 = lane * 2;
    float sgx = 0.f, sgy = 0.f, spx = 0.f, spy = 0.f;

    for (int w = beg0; w < end3; w += AWIN) {
        const int cnt = min(AWIN, end3 - w);
        __syncthreads();
        for (int i = tid; i < cnt; i += 256)
            sm[i] = __builtin_nontemporal_load((const i32x4*)meta + w + i);
        __syncthreads();
        int t = max(beg, w);
        const int hi = min(end, w + cnt);
        for (; t + 8 <= hi; t += 8) {
            i32x4 m[8];
#pragma unroll
            for (int q = 0; q < 8; ++q) m[q] = sm[t - w + q];
            unsigned u[8];
#pragma unroll
            for (int q = 0; q < 8; ++q)
                u[q] = *(const unsigned*)(hw1 + ((size_t)(unsigned)m[q].x << 7) + f2);
#pragma unroll
            for (int q = 0; q < 8; ++q) {
                float2 h = bf2_to_f2(u[q]);
                float wg = __uint_as_float((unsigned)m[q].y);
                float wp = __uint_as_float((unsigned)m[q].z);
                sgx += wg * h.x; sgy += wg * h.y;
                spx += wp * h.x; spy += wp * h.y;
            }
        }
        if (t + 4 <= hi) {
            i32x4 m[4];
#pragma unroll
            for (int q = 0; q < 4; ++q) m[q] = sm[t - w + q];
            unsigned u[4];
#pragma unroll
            for (int q = 0; q < 4; ++q)
                u[q] = *(const unsigned*)(hw1 + ((size_t)(unsigned)m[q].x << 7) + f2);
#pragma unroll
            for (int q = 0; q < 4; ++q) {
                float2 h = bf2_to_f2(u[q]);
                float wg = __uint_as_float((unsigned)m[q].y);
                float wp = __uint_as_float((unsigned)m[q].z);
                sgx += wg * h.x; sgy += wg * h.y;
                spx += wp * h.x; spy += wp * h.y;
            }
            t += 4;
        }
        for (; t < hi; ++t) {
            i32x4 m0 = sm[t - w];
            float2 h0 = bf2_to_f2(*(const unsigned*)(hw1 + ((size_t)(unsigned)m0.x << 7) + f2));
            float wg0 = __uint_as_float((unsigned)m0.y);
            float wp0 = __uint_as_float((unsigned)m0.z);
            sgx += wg0 * h0.x; sgy += wg0 * h0.y;
            spx += wp0 * h0.x; spy += wp0 * h0.y;
        }
    }

    if (c < n) {
        float2 d = dis[c];
        size_t idx = ((size_t)c << 7) + f2;
        float2 hs = bf2_to_f2(*(const unsigned*)(hw1 + idx));
        float2 bv = *(const float2*)(b1 + f2);
        float gx = d.x * sgx + d.x * d.x * hs.x + bv.x;
        float gy = d.x * sgy + d.x * d.x * hs.y + bv.y;
        float px = d.y * spx + d.y * d.y * hs.x + bv.x;
        float py = d.y * spy + d.y * d.y * hs.y + bv.y;
        f32x2 go, po;
        go[0] = gx > 0.f ? gx : 0.f;  go[1] = gy > 0.f ? gy : 0.f;
        po[0] = px > 0.f ? px : 0.f;  po[1] = py > 0.f ? py : 0.f;
        __builtin_nontemporal_store(go, (f32x2*)(g_out + idx));
        __builtin_nontemporal_store(po, (f32x2*)(p_out + idx));
    }
}

// ---------------------------------------------------------------------------
// Layer-2 pull aggregation + self-loop + bias + softmax gate.
// hw2i layout: [n][64][2] bf16; LDS meta staging as agg1.
// ---------------------------------------------------------------------------
__global__ void agg2_final_kernel(const int* __restrict__ row_ptr, const int4* __restrict__ meta,
                                  const __bf16* __restrict__ hw2i,
                                  const float2* __restrict__ dis,
                                  const float* __restrict__ b2,
                                  const float* __restrict__ dense_w, const float* __restrict__ dense_b,
                                  float* __restrict__ out, int n) {
    __shared__ i32x4 sm[AWIN];
    const int tid  = threadIdx.x;
    const int wave = tid >> 6;
    const int f    = tid & 63;
    const int c0   = blockIdx.x * 4;
    const int c    = c0 + wave;
    const int beg0 = row_ptr[c0];
    const int end3 = row_ptr[min(c0 + 4, n)];
    int beg = 0, end = 0;
    if (c < n) { beg = row_ptr[c]; end = row_ptr[c + 1]; }
    const int f2 = f * 2;
    float sg = 0.f, sp = 0.f;

    for (int w = beg0; w < end3; w += AWIN) {
        const int cnt = min(AWIN, end3 - w);
        __syncthreads();
        for (int i = tid; i < cnt; i += 256)
            sm[i] = __builtin_nontemporal_load((const i32x4*)meta + w + i);
        __syncthreads();
        int t = max(beg, w);
        const int hi = min(end, w + cnt);
        for (; t + 8 <= hi; t += 8) {
            i32x4 m[8];
#pragma unroll
            for (int q = 0; q < 8; ++q) m[q] = sm[t - w + q];
            unsigned u[8];
#pragma unroll
            for (int q = 0; q < 8; ++q)
                u[q] = *(const unsigned*)(hw2i + ((size_t)(unsigned)m[q].x << 7) + f2);
#pragma unroll
            for (int q = 0; q < 8; ++q) {
                float2 g0 = bf2_to_f2(u[q]);
                sg += __uint_as_float((unsigned)m[q].y) * g0.x;
                sp += __uint_as_float((unsigned)m[q].z) * g0.y;
            }
        }
        if (t + 4 <= hi) {
            i32x4 m[4];
#pragma unroll
            for (int q = 0; q < 4; ++q) m[q] = sm[t - w + q];
            unsigned u[4];
#pragma unroll
            for (int q = 0; q < 4; ++q)
                u[q] = *(const unsigned*)(hw2i + ((size_t)(unsigned)m[q].x << 7) + f2);
#pragma unroll
            for (int q = 0; q < 4; ++q) {
                float2 g0 = bf2_to_f2(u[q]);
                sg += __uint_as_float((unsigned)m[q].y) * g0.x;
                sp += __uint_as_float((unsigned)m[q].z) * g0.y;
            }
            t += 4;
        }
        for (; t < hi; ++t) {
            i32x4 m0 = sm[t - w];
            float2 g0 = bf2_to_f2(*(const unsigned*)(hw2i + ((size_t)(unsigned)m0.x << 7) + f2));
            sg += __uint_as_float((unsigned)m0.y) * g0.x;
            sp += __uint_as_float((unsigned)m0.z) * g0.y;
        }
    }

    if (c < n) {
        float2 d = dis[c];
        float2 gps = bf2_to_f2(*(const unsigned*)(hw2i + ((size_t)c << 7) + f2));
        float bb = b2[f];
        float gv = d.x * sg + d.x * d.x * gps.x + bb;
        float pv = d.y * sp + d.y * d.y * gps.y + bb;
        float dwv = dense_w[f];
        float lg = gv * dwv, lp = pv * dwv;
#pragma unroll
        for (int off = 32; off > 0; off >>= 1) {
            lg += __shfl_xor(lg, off, 64);
            lp += __shfl_xor(lp, off, 64);
        }
        lg += dense_b[0];
        lp += dense_b[0];
        float m  = fmaxf(lg, lp);
        float eg = expf(lg - m), ep = expf(lp - m);
        float wgt = eg / (eg + ep);
        __builtin_nontemporal_store(wgt * gv + (1.0f - wgt) * pv, out + (size_t)c * OO + f);
    }
}

// ---------------------------------------------------------------------------
extern "C" void kernel_launch(void* const* d_in, const int* in_sizes, int n_in,
                              void* d_out, int out_size, void* d_ws, size_t ws_size,
                              hipStream_t stream) {
    const float* x    = (const float*)d_in[0];
    const int*   ei   = (const int*)d_in[1];
    const float* ppmi = (const float*)d_in[2];
    const float* W1   = (const float*)d_in[3];
    const float* b1   = (const float*)d_in[4];
    const float* W2   = (const float*)d_in[5];
    const float* b2   = (const float*)d_in[6];
    const float* dw   = (const float*)d_in[7];
    const float* db   = (const float*)d_in[8];
    float* out = (float*)d_out;

    const int n = in_sizes[0] / DD;       // 100000
    const int e = in_sizes[2];            // 1600000
    const int* row = ei;
    const int* col = ei + e;

    const int nb   = (n + BKT - 1) / BKT;   // buckets (<=256 required)
    const int nblk = (e + EPB - 1) / EPB;   // partition blocks (<=256 required)

    // ---- workspace layout ----
    float* ws      = (float*)d_ws;
    float2* dis    = (float2*)ws;                     // n float2
    __bf16* hw1    = (__bf16*)(ws + 2 * (size_t)n);   // n*128 bf16 (aliased as hw2i [n][64][2])
    float* g1      = (float*)(hw1 + (size_t)n * HH);  // n*128 f32 (tmp_col aliases: int4[e])
    float* p1      = g1 + (size_t)n * HH;             // n*128 f32 (tmp_row aliases: int2[e])
    int4* csr_meta = (int4*)(p1 + (size_t)n * HH);    // e int4 {src, wg, wp, 0}
    __bf16* bt1h   = (__bf16*)(csr_meta + e);         // DD*HH
    __bf16* bt1l   = bt1h + (size_t)DD * HH;
    __bf16* bt2h   = bt1l + (size_t)DD * HH;          // HH*OO
    __bf16* bt2l   = bt2h + (size_t)HH * OO;
    int* row_ptr   = (int*)(bt2l + (size_t)HH * OO);  // n+1
    int* cnt_col   = row_ptr + (n + 1);               // nblk*nb
    int* base_col  = cnt_col + (size_t)nblk * nb;     // nblk*nb
    int* cnt_row   = base_col + (size_t)nblk * nb;    // nblk*nb
    int* base_row  = cnt_row + (size_t)nblk * nb;     // nblk*nb
    int* bb_col    = base_row + (size_t)nblk * nb;    // nb
    int* tot_col   = bb_col + nb;                     // nb
    int* bb_row    = tot_col + nb;                    // nb
    int* tot_row   = bb_row + nb;                     // nb
    int4* tmp_col  = (int4*)g1;                       // e (alias, dead before agg1 writes g1)
    int2* tmp_row  = (int2*)p1;                       // e (alias, dead before agg1 writes p1)
    __bf16* hw2i   = hw1;                             // [n][64][2] bf16 (hw1 dead after agg1)

    const int T = 256;

    // ---- partition pipeline (LDS atomics only, fully parallel scans) ----
    part_count_kernel<<<nblk, 512, 0, stream>>>(row, col, e, nb, cnt_col, cnt_row);
    scan_blocks_kernel<<<2 * nb, T, 0, stream>>>(cnt_col, cnt_row, base_col, base_row,
                                                 tot_col, tot_row, nblk, nb);
    add_bases_kernel<<<2 * nb, T, 0, stream>>>(base_col, base_row, tot_col, tot_row,
                                               bb_col, bb_row, row_ptr, n, e, nblk, nb);
    part_scatter_kernel<<<nblk, 512, 0, stream>>>(row, col, ppmi, base_col, base_row,
                                                  tmp_col, tmp_row, e, nb);
    deg_bucket_kernel<<<nb, 512, 0, stream>>>(tmp_row, bb_row, tot_row, dis, n);
    csr_bucket_kernel<<<nb, BKT, 0, stream>>>(tmp_col, bb_col, tot_col, dis,
                                              row_ptr, csr_meta, n);

    // ---- weight prep ----
    conv_w_kernel<<<(DD * HH + T - 1) / T, T, 0, stream>>>(W1, bt1h, bt1l, DD, HH);
    conv_w_kernel<<<(HH * OO + T - 1) / T, T, 0, stream>>>(W2, bt2h, bt2l, HH, OO);

    // ---- network ----
    mfma_gemm_kernel<128, HH, __bf16, false><<<(n + 127) / 128, 256, 0, stream>>>(
        x, bt1h, bt1l, hw1, n, DD, 0);
    agg1_pull_kernel<<<(n + 3) / 4, 256, 0, stream>>>(row_ptr, csr_meta, hw1, dis, b1, g1, p1, n);
    mfma_gemm_kernel<128, OO, __bf16, true><<<(2 * n + 127) / 128, 256, 0, stream>>>(
        g1, bt2h, bt2l, hw2i, 2 * n, HH, n);
    agg2_final_kernel<<<(n + 3) / 4, 256, 0, stream>>>(row_ptr, csr_meta, hw2i, dis,
                                                       b2, dw, db, out, n);
}